// Round 6
// baseline (277.664 us; speedup 1.0000x reference)
//
#include <hip/hip_runtime.h>

// LSSM via truncated causal convolution (rho(A)=0.9 => A^128 ~ 1e-6, negligible).
//   W_0 = CB + D, W_d = C A^d B;  y_t = sum_{s<=t} u_s W_{t-s}^T
// Chunked CL=8 (NCH=1024 chunks):
//   pass1: E1_c = U_c @ Kbig          (Kbig block i = A^{7-i}B)        GEMM M=16384 K=1024 N=128
//   passE: Xent_c = sum_{j=1..16} E1_{c-j} (A^{8(j-1)})^T  (window-16) GEMM M=16384 K=2048 N=128
//   pass2: Y_c = [U_c | Xent_c] @ Wext (block-triangular + Q=CA^{t+1}) GEMM M=16384 K<=1152 N=1024
// No serial scan anywhere. Prep: k_squares (A^2..A^64 in-LDS chain) + k_mats
// (40 parallel blocks, each <=4 chained in-block 128^3 matmuls, packs bf16).
// All B-matrices stored "transposed" (row n, col k) for row-contiguous staging.
// LDS tiles XOR-swizzled (granule 8 bf16) to kill ds_read_b128 bank conflicts.

#define SEQ 8192
#define DD  128
#define NCH 1024
#define WIN 16

typedef __bf16 bf16t;
typedef __bf16 bf16x8 __attribute__((ext_vector_type(8)));
typedef float  f32x4  __attribute__((ext_vector_type(4)));

#define MFMA(a,b,c) __builtin_amdgcn_mfma_f32_16x16x32_bf16(a,b,c,0,0,0)

// swizzled column index within a row; granule = 8 bf16 = 16B
__device__ __forceinline__ int swc(int r, int c) {
    int g = c >> 3;
    g = (g & ~7) | ((g ^ r) & 7);
    return (g << 3) | (c & 7);
}
__device__ __forceinline__ bf16x8 ldf64(const bf16t* T, int row, int q, int lane) {
    int c = q * 32 + ((lane >> 4) << 3);
    return *(const bf16x8*)(T + row * 64 + swc(row, c));
}
__device__ __forceinline__ bf16x8 ldf128(const bf16t* T, int row, int q, int lane) {
    int c = q * 32 + ((lane >> 4) << 3);
    return *(const bf16x8*)(T + row * 128 + swc(row, c));
}
__device__ __forceinline__ bf16x8 cvt8(float4 a, float4 b) {
    bf16x8 r;
    r[0]=(bf16t)a.x; r[1]=(bf16t)a.y; r[2]=(bf16t)a.z; r[3]=(bf16t)a.w;
    r[4]=(bf16t)b.x; r[5]=(bf16t)b.y; r[6]=(bf16t)b.z; r[7]=(bf16t)b.w;
    return r;
}
__device__ __forceinline__ bf16x8 bzero8() {
    bf16x8 z;
#pragma unroll
    for (int e = 0; e < 8; e++) z[e] = (bf16t)0.f;
    return z;
}
__device__ __forceinline__ f32x4 fzero4() { f32x4 z = {0.f, 0.f, 0.f, 0.f}; return z; }

// ---------------- k_squares: block 0: A^2,A^4,A^8,A^16,A^32,A^64 (in-LDS chain);
// blocks >0: zero Wext; block 1 also writes identity ----------------
__global__ __launch_bounds__(512, 2) void k_squares(const float* __restrict__ A,
                                                    float* __restrict__ Sq,
                                                    float* __restrict__ Iden,
                                                    bf16t* __restrict__ Wext) {
    if (blockIdx.x > 0) {
        bf16x8 z = bzero8();
        long t0 = (long)(blockIdx.x - 1) * 512 + threadIdx.x;
        const long tot = 1024L * 1152 / 8;
        for (long i = t0; i < tot; i += (long)(gridDim.x - 1) * 512)
            *(bf16x8*)(Wext + i * 8) = z;
        if (blockIdx.x == 1)
            for (int i = threadIdx.x; i < 16384; i += 512)
                Iden[i] = ((i >> 7) == (i & 127)) ? 1.f : 0.f;
        return;
    }
    __shared__ bf16t H0[128*128], T0[128*128], H1[128*128], T1[128*128];  // 128 KB
    int tid = threadIdx.x, lane = tid & 63, wid = tid >> 6;
    {   // load A -> H0 (row-major swz) and T0 (transposed swz)
        int r = tid >> 2, c0 = (tid & 3) * 32;
#pragma unroll
        for (int e = 0; e < 4; e++) {
            float4 va = *(const float4*)(A + r*128 + c0 + e*8);
            float4 vb = *(const float4*)(A + r*128 + c0 + e*8 + 4);
            bf16x8 h = cvt8(va, vb);
            *(bf16x8*)(H0 + r*128 + swc(r, c0 + e*8)) = h;
#pragma unroll
            for (int x = 0; x < 8; x++) {
                int cc = c0 + e*8 + x;
                T0[cc*128 + swc(cc, r)] = h[x];
            }
        }
    }
    __syncthreads();
    bf16t *cH = H0, *cT = T0, *nH = H1, *nT = T1;
    for (int lvl = 0; lvl < 6; lvl++) {
        f32x4 acc[8];
#pragma unroll
        for (int nf = 0; nf < 8; nf++) acc[nf] = fzero4();
        int m = 16*wid + (lane & 15);
#pragma unroll
        for (int q = 0; q < 4; q++) {
            bf16x8 af = ldf128(cH, m, q, lane);
#pragma unroll
            for (int nf = 0; nf < 8; nf++) {
                bf16x8 bv = ldf128(cT, nf*16 + (lane & 15), q, lane);
                acc[nf] = MFMA(af, bv, acc[nf]);
            }
        }
#pragma unroll
        for (int nf = 0; nf < 8; nf++)
#pragma unroll
            for (int rr = 0; rr < 4; rr++) {
                int row = 16*wid + ((lane >> 4) << 2) + rr;
                int col = nf*16 + (lane & 15);
                float v = acc[nf][rr];
                bf16t hv = (bf16t)v;
                nH[row*128 + swc(row, col)] = hv;
                nT[col*128 + swc(col, row)] = hv;
                Sq[lvl*16384 + row*128 + col] = v;
            }
        __syncthreads();
        bf16t* t;
        t = cH; cH = nH; nH = t;
        t = cT; cT = nT; nT = t;
    }
}

// ---------------- k_mats: 40 blocks, each a chain product, packed bf16 ----------------
// globals: 0=A 1=B 2=C 3=A2 4=A4 5=A8 6=A16 7=A32 8=A64 9=I
__global__ __launch_bounds__(512, 2) void k_mats(const float* __restrict__ A,
                                                 const float* __restrict__ B,
                                                 const float* __restrict__ C,
                                                 const float* __restrict__ Dm,
                                                 const float* __restrict__ Sq,
                                                 const float* __restrict__ Iden,
                                                 bf16t* __restrict__ Kbig,
                                                 bf16t* __restrict__ Dist,
                                                 bf16t* __restrict__ Wext) {
    __shared__ bf16t Hc[128*128], Hn[128*128];   // 64 KB
    int tid = threadIdx.x, lane = tid & 63, wid = tid >> 6;
    int bid = blockIdx.x;
    const float* G[10] = {A, B, C, Sq, Sq + 16384, Sq + 2*16384,
                          Sq + 3*16384, Sq + 4*16384, Sq + 5*16384, Iden};
    int ch[6]; int nc = 0;
    bf16t* dst0 = nullptr; long dstride = 0;
    bool plusD = false, isW = false; int wd = 0;
    if (bid < 14) {                       // P^j = A^(8j) -> Dist col-block 15-j
        int j = bid + 2;
        if (j & 8) ch[nc++] = 8;
        if (j & 4) ch[nc++] = 7;
        if (j & 2) ch[nc++] = 6;
        if (j & 1) ch[nc++] = 5;
        if (nc == 1) ch[nc++] = 9;
        dst0 = Dist + (15 - j) * 128; dstride = 2048;
    } else if (bid == 14) { ch[nc++] = 9; ch[nc++] = 9; dst0 = Dist + 15*128; dstride = 2048; }
    else if (bid == 15)   { ch[nc++] = 5; ch[nc++] = 9; dst0 = Dist + 14*128; dstride = 2048; }
    else if (bid < 24) {                  // S_d = A^d B -> Kbig col-block 7-d
        int d = bid - 16;
        if (d & 4) ch[nc++] = 4;
        if (d & 2) ch[nc++] = 3;
        if (d & 1) ch[nc++] = 0;
        ch[nc++] = 1;
        if (nc == 1) ch[nc++] = 9;
        dst0 = Kbig + (7 - d) * 128; dstride = 1024;
    } else if (bid < 32) {                // Q_k = C A^k -> Wext rows (k-1)*128, col 1024
        int k = bid - 23;
        ch[nc++] = 2;
        if (k & 8) ch[nc++] = 5;
        if (k & 4) ch[nc++] = 4;
        if (k & 2) ch[nc++] = 3;
        if (k & 1) ch[nc++] = 0;
        dst0 = Wext + (long)(k - 1) * 128 * 1152 + 1024; dstride = 1152;
    } else {                              // W_d = C A^d B (+D if d=0) -> slots (t, t-d)
        wd = bid - 32; isW = true;
        ch[nc++] = 2;
        if (wd & 4) ch[nc++] = 4;
        if (wd & 2) ch[nc++] = 3;
        if (wd & 1) ch[nc++] = 0;
        ch[nc++] = 1;
        plusD = (wd == 0);
    }
    {   // stage G[ch[0]] into Hc
        const float* g0 = G[ch[0]];
        int r = tid >> 2, c0 = (tid & 3) * 32;
#pragma unroll
        for (int e = 0; e < 4; e++) {
            float4 va = *(const float4*)(g0 + r*128 + c0 + e*8);
            float4 vb = *(const float4*)(g0 + r*128 + c0 + e*8 + 4);
            *(bf16x8*)(Hc + r*128 + swc(r, c0 + e*8)) = cvt8(va, vb);
        }
    }
    __syncthreads();
    f32x4 acc[8];
    bf16t* cur = Hc; bf16t* nxt = Hn;
    for (int i = 1; i < nc; i++) {
        const float* g = G[ch[i]];
#pragma unroll
        for (int nf = 0; nf < 8; nf++) acc[nf] = fzero4();
        int m = 16*wid + (lane & 15);
        int n0 = lane & 15;
#pragma unroll
        for (int q = 0; q < 4; q++) {
            bf16x8 af = ldf128(cur, m, q, lane);
            int kb = q*32 + ((lane >> 4) << 3);
#pragma unroll
            for (int nf = 0; nf < 8; nf++) {
                bf16x8 bv;
#pragma unroll
                for (int e = 0; e < 8; e++) bv[e] = (bf16t)g[(kb + e)*128 + nf*16 + n0];
                acc[nf] = MFMA(af, bv, acc[nf]);
            }
        }
        if (i + 1 < nc) {
#pragma unroll
            for (int nf = 0; nf < 8; nf++)
#pragma unroll
                for (int rr = 0; rr < 4; rr++) {
                    int row = 16*wid + ((lane >> 4) << 2) + rr;
                    int col = nf*16 + (lane & 15);
                    nxt[row*128 + swc(row, col)] = (bf16t)acc[nf][rr];
                }
            __syncthreads();
            bf16t* t = cur; cur = nxt; nxt = t;
        }
    }
#pragma unroll
    for (int nf = 0; nf < 8; nf++)
#pragma unroll
        for (int rr = 0; rr < 4; rr++) {
            int row = 16*wid + ((lane >> 4) << 2) + rr;
            int col = nf*16 + (lane & 15);
            float v = acc[nf][rr];
            if (plusD) v += Dm[row*128 + col];
            bf16t hv = (bf16t)v;
            if (!isW) dst0[(long)row * dstride + col] = hv;
            else
                for (int t = wd; t < 8; t++)
                    Wext[((long)t*128 + row) * 1152 + (t - wd)*128 + col] = hv;
        }
}

// ---------------- pass1: E1 = U @ Kbig ; BM=64(4 chunks) BN=128 BK=64, 4 waves ----------------
__global__ __launch_bounds__(256, 2) void k_pass1(const float* __restrict__ u,
                                                  const bf16t* __restrict__ Kbig,
                                                  bf16t* __restrict__ E1) {
    __shared__ bf16t As[2][64*64], Bs[2][128*64];    // 48 KB
    int tid = threadIdx.x, lane = tid & 63, wid = tid >> 6;
    int wm = wid >> 1, wn = wid & 1;
    int c0 = blockIdx.x * 4;
    int ar = tid >> 2, akq = (tid & 3) << 4;
    int br = tid >> 1, bkh = (tid & 1) << 5;
    const float* ua = u + (long)(ar & 15) * SEQ * DD + (long)(c0 + (ar >> 4)) * (8 * DD) + akq;
    const bf16t* bb = Kbig + br * 1024 + bkh;
    f32x4 acc[2][4];
#pragma unroll
    for (int a = 0; a < 2; a++)
#pragma unroll
        for (int nf = 0; nf < 4; nf++) acc[a][nf] = fzero4();
    {   // stage ss=0
        float4 v0 = *(const float4*)(ua);
        float4 v1 = *(const float4*)(ua + 4);
        float4 v2 = *(const float4*)(ua + 8);
        float4 v3 = *(const float4*)(ua + 12);
        *(bf16x8*)(As[0] + ar*64 + swc(ar, akq))     = cvt8(v0, v1);
        *(bf16x8*)(As[0] + ar*64 + swc(ar, akq + 8)) = cvt8(v2, v3);
#pragma unroll
        for (int e = 0; e < 4; e++)
            *(bf16x8*)(Bs[0] + br*64 + swc(br, bkh + e*8)) = *(const bf16x8*)(bb + e*8);
    }
    __syncthreads();
    for (int ss = 0; ss < 16; ss++) {
        int p = ss & 1;
        float4 v0, v1, v2, v3; bf16x8 bv[4];
        if (ss + 1 < 16) {
            const float* pa = ua + (ss + 1) * 64;
            v0 = *(const float4*)(pa);     v1 = *(const float4*)(pa + 4);
            v2 = *(const float4*)(pa + 8); v3 = *(const float4*)(pa + 12);
#pragma unroll
            for (int e = 0; e < 4; e++) bv[e] = *(const bf16x8*)(bb + (ss + 1)*64 + e*8);
        }
#pragma unroll
        for (int q = 0; q < 2; q++) {
            bf16x8 af[2];
#pragma unroll
            for (int a = 0; a < 2; a++) af[a] = ldf64(As[p], wm*32 + a*16 + (lane & 15), q, lane);
#pragma unroll
            for (int nf = 0; nf < 4; nf++) {
                bf16x8 bfv = ldf64(Bs[p], wn*64 + nf*16 + (lane & 15), q, lane);
#pragma unroll
                for (int a = 0; a < 2; a++) acc[a][nf] = MFMA(af[a], bfv, acc[a][nf]);
            }
        }
        if (ss + 1 < 16) {
            *(bf16x8*)(As[p^1] + ar*64 + swc(ar, akq))     = cvt8(v0, v1);
            *(bf16x8*)(As[p^1] + ar*64 + swc(ar, akq + 8)) = cvt8(v2, v3);
#pragma unroll
            for (int e = 0; e < 4; e++)
                *(bf16x8*)(Bs[p^1] + br*64 + swc(br, bkh + e*8)) = bv[e];
        }
        __syncthreads();
    }
#pragma unroll
    for (int a = 0; a < 2; a++) {
        int chunk = c0 + wm*2 + a;
#pragma unroll
        for (int nf = 0; nf < 4; nf++)
#pragma unroll
            for (int rr = 0; rr < 4; rr++) {
                int b = ((lane >> 4) << 2) + rr;
                int n = wn*64 + nf*16 + (lane & 15);
                E1[((long)chunk*16 + b)*128 + n] = (bf16t)acc[a][nf][rr];
            }
    }
}

// ---------------- passE: Xent = window-16 of E1 @ Dist ----------------
__global__ __launch_bounds__(256, 2) void k_passE(const bf16t* __restrict__ E1,
                                                  const bf16t* __restrict__ Dist,
                                                  bf16t* __restrict__ Xent) {
    __shared__ bf16t As[2][64*64], Bs[2][128*64];
    int tid = threadIdx.x, lane = tid & 63, wid = tid >> 6;
    int wm = wid >> 1, wn = wid & 1;
    int c0 = blockIdx.x * 4;
    int ar = tid >> 2, akq = (tid & 3) << 4;
    int arc = ar >> 4, arb = ar & 15;
    int br = tid >> 1, bkh = (tid & 1) << 5;
    const bf16t* bb = Dist + br * 2048 + bkh;
    f32x4 acc[2][4];
#pragma unroll
    for (int a = 0; a < 2; a++)
#pragma unroll
        for (int nf = 0; nf < 4; nf++) acc[a][nf] = fzero4();
    {   // stage ss=0 (window w=0, half 0)
        int sc = c0 + arc - WIN;
        bf16x8 h0 = bzero8(), h1 = bzero8();
        if (sc >= 0) {
            const bf16t* src = E1 + ((long)sc*16 + arb)*128 + akq;
            h0 = *(const bf16x8*)(src); h1 = *(const bf16x8*)(src + 8);
        }
        *(bf16x8*)(As[0] + ar*64 + swc(ar, akq))     = h0;
        *(bf16x8*)(As[0] + ar*64 + swc(ar, akq + 8)) = h1;
#pragma unroll
        for (int e = 0; e < 4; e++)
            *(bf16x8*)(Bs[0] + br*64 + swc(br, bkh + e*8)) = *(const bf16x8*)(bb + e*8);
    }
    __syncthreads();
    for (int ss = 0; ss < 32; ss++) {
        int p = ss & 1;
        bf16x8 h0, h1, bv[4];
        if (ss + 1 < 32) {
            int s1 = ss + 1;
            int sc = c0 + arc - WIN + (s1 >> 1);
            h0 = bzero8(); h1 = bzero8();
            if (sc >= 0) {
                const bf16t* src = E1 + ((long)sc*16 + arb)*128 + (s1 & 1)*64 + akq;
                h0 = *(const bf16x8*)(src); h1 = *(const bf16x8*)(src + 8);
            }
#pragma unroll
            for (int e = 0; e < 4; e++) bv[e] = *(const bf16x8*)(bb + s1*64 + e*8);
        }
#pragma unroll
        for (int q = 0; q < 2; q++) {
            bf16x8 af[2];
#pragma unroll
            for (int a = 0; a < 2; a++) af[a] = ldf64(As[p], wm*32 + a*16 + (lane & 15), q, lane);
#pragma unroll
            for (int nf = 0; nf < 4; nf++) {
                bf16x8 bfv = ldf64(Bs[p], wn*64 + nf*16 + (lane & 15), q, lane);
#pragma unroll
                for (int a = 0; a < 2; a++) acc[a][nf] = MFMA(af[a], bfv, acc[a][nf]);
            }
        }
        if (ss + 1 < 32) {
            *(bf16x8*)(As[p^1] + ar*64 + swc(ar, akq))     = h0;
            *(bf16x8*)(As[p^1] + ar*64 + swc(ar, akq + 8)) = h1;
#pragma unroll
            for (int e = 0; e < 4; e++)
                *(bf16x8*)(Bs[p^1] + br*64 + swc(br, bkh + e*8)) = bv[e];
        }
        __syncthreads();
    }
#pragma unroll
    for (int a = 0; a < 2; a++) {
        int chunk = c0 + wm*2 + a;
#pragma unroll
        for (int nf = 0; nf < 4; nf++)
#pragma unroll
            for (int rr = 0; rr < 4; rr++) {
                int b = ((lane >> 4) << 2) + rr;
                int n = wn*64 + nf*16 + (lane & 15);
                Xent[((long)chunk*16 + b)*128 + n] = (bf16t)acc[a][nf][rr];
            }
    }
}

// ---------------- pass2: Y = [U|Xent] @ Wext ; BM=256(16 chunks) BN=128(one t) ----------------
// 8 waves (4 wm x 2 wn); paired t-jobs {p, 7-p} => uniform 22 substeps/block.
// XCD-swizzle: the 4 p-blocks of one gm land on the same XCD for u L2-reuse.
__global__ __launch_bounds__(512, 2) void k_pass2(const float* __restrict__ u,
                                                  const bf16t* __restrict__ Xent,
                                                  const bf16t* __restrict__ Wext,
                                                  float* __restrict__ out) {
    __shared__ bf16t As[2][256*64], Bs[2][128*64];   // 96 KB
    int tid = threadIdx.x, lane = tid & 63, wid = tid >> 6;
    int wm = wid >> 1, wn = wid & 1;
    int i = blockIdx.x;
    int gm = (i & 7) * 8 + ((i >> 3) >> 2);
    int pp = (i >> 3) & 3;
    int c0 = gm * 16;
    int ar = tid >> 1, akh = (tid & 1) << 5;
    int arc = ar >> 4, arb = ar & 15;
    int br = tid >> 2, bkq = (tid & 3) << 4;
    const float* ua = u + (long)arb * SEQ * DD + (long)(c0 + arc) * (8 * DD) + akh;
    const bf16t* xa = Xent + ((long)(c0 + arc) * 16 + arb) * 128 + akh;

    for (int job = 0; job < 2; job++) {
        int t = job ? (7 - pp) : pp;
        const bf16t* bb = Wext + (long)(t * 128 + br) * 1152 + bkq;
        int NS = 2*t + 4;
        int nu = 2*t + 2;                 // u-substeps; then 2 xent substeps
        f32x4 acc[4][4];
#pragma unroll
        for (int a = 0; a < 4; a++)
#pragma unroll
            for (int nf = 0; nf < 4; nf++) acc[a][nf] = fzero4();
        {   // stage ss=0 (always a u-substep)
            float4 v[8];
#pragma unroll
            for (int e = 0; e < 8; e++) v[e] = *(const float4*)(ua + e*4);
#pragma unroll
            for (int e = 0; e < 4; e++)
                *(bf16x8*)(As[0] + ar*64 + swc(ar, akh + e*8)) = cvt8(v[2*e], v[2*e+1]);
            *(bf16x8*)(Bs[0] + br*64 + swc(br, bkq))     = *(const bf16x8*)(bb);
            *(bf16x8*)(Bs[0] + br*64 + swc(br, bkq + 8)) = *(const bf16x8*)(bb + 8);
        }
        __syncthreads();
        for (int ss = 0; ss < NS; ss++) {
            int p = ss & 1;
            float4 v[8]; bf16x8 xv[4], bv0, bv1;
            bool nxU = true;
            if (ss + 1 < NS) {
                int s1 = ss + 1;
                nxU = s1 < nu;
                if (nxU) {
                    const float* pa = ua + s1 * 64;
#pragma unroll
                    for (int e = 0; e < 8; e++) v[e] = *(const float4*)(pa + e*4);
                } else {
                    const bf16t* px = xa + (s1 - nu) * 64;
#pragma unroll
                    for (int e = 0; e < 4; e++) xv[e] = *(const bf16x8*)(px + e*8);
                }
                long kB = nxU ? (long)s1 * 64 : 1024 + (long)(s1 - nu) * 64;
                bv0 = *(const bf16x8*)(bb + kB);
                bv1 = *(const bf16x8*)(bb + kB + 8);
            }
#pragma unroll
            for (int q = 0; q < 2; q++) {
                bf16x8 af[4];
#pragma unroll
                for (int a = 0; a < 4; a++)
                    af[a] = ldf64(As[p], wm*64 + a*16 + (lane & 15), q, lane);
#pragma unroll
                for (int nf = 0; nf < 4; nf++) {
                    bf16x8 bfv = ldf64(Bs[p], wn*64 + nf*16 + (lane & 15), q, lane);
#pragma unroll
                    for (int a = 0; a < 4; a++) acc[a][nf] = MFMA(af[a], bfv, acc[a][nf]);
                }
            }
            if (ss + 1 < NS) {
                if (nxU) {
#pragma unroll
                    for (int e = 0; e < 4; e++)
                        *(bf16x8*)(As[p^1] + ar*64 + swc(ar, akh + e*8)) = cvt8(v[2*e], v[2*e+1]);
                } else {
#pragma unroll
                    for (int e = 0; e < 4; e++)
                        *(bf16x8*)(As[p^1] + ar*64 + swc(ar, akh + e*8)) = xv[e];
                }
                *(bf16x8*)(Bs[p^1] + br*64 + swc(br, bkq))     = bv0;
                *(bf16x8*)(Bs[p^1] + br*64 + swc(br, bkq + 8)) = bv1;
            }
            __syncthreads();
        }
#pragma unroll
        for (int a = 0; a < 4; a++) {
            int cl = wm*4 + a;
#pragma unroll
            for (int nf = 0; nf < 4; nf++)
#pragma unroll
                for (int rr = 0; rr < 4; rr++) {
                    int b = ((lane >> 4) << 2) + rr;
                    int dout = wn*64 + nf*16 + (lane & 15);
                    out[((long)b*SEQ + (long)(c0 + cl)*8 + t)*128 + dout] = acc[a][nf][rr];
                }
        }
        __syncthreads();
    }
}

extern "C" void kernel_launch(void* const* d_in, const int* in_sizes, int n_in,
                              void* d_out, int out_size, void* d_ws, size_t ws_size,
                              hipStream_t stream) {
    (void)in_sizes; (void)n_in; (void)out_size; (void)ws_size;
    const float* u = (const float*)d_in[0];
    const float* A = (const float*)d_in[1];
    const float* B = (const float*)d_in[2];
    const float* C = (const float*)d_in[3];
    const float* D = (const float*)d_in[4];
    float* out = (float*)d_out;
    // ws: Sq 6x16K f32 | Iden 16K f32 | Kbig 128x1024 bf16 | Dist 128x2048 bf16
    //   | Wext 1024x1152 bf16 | Xent 1024x16x128 bf16   (~7.44 MB)
    float* Sq   = (float*)d_ws;
    float* Iden = Sq + 6 * 16384;
    bf16t* Kbig = (bf16t*)(Iden + 16384);
    bf16t* Dist = Kbig + 128 * 1024;
    bf16t* Wext = Dist + 128 * 2048;
    bf16t* Xent = Wext + (long)1024 * 1152;
    bf16t* E1   = (bf16t*)d_out;   // borrowed: dead before pass2 overwrites out

    k_squares<<<65, 512, 0, stream>>>(A, Sq, Iden, Wext);
    k_mats  <<<40, 512, 0, stream>>>(A, B, C, D, Sq, Iden, Kbig, Dist, Wext);
    k_pass1 <<<256, 256, 0, stream>>>(u, Kbig, E1);
    k_passE <<<256, 256, 0, stream>>>(E1, Dist, Xent);
    k_pass2 <<<256, 512, 0, stream>>>(u, Xent, Wext, out);
}

// Round 7
// 156.483 us; speedup vs baseline: 1.7744x; 1.7744x over previous
//
#include <hip/hip_runtime.h>

// LSSM via truncated causal convolution (rho(A)=0.9 => A^128 ~ 1e-6, negligible).
//   W_0 = CB + D, W_d = C A^d B;  y_t = sum_{s<=t} u_s W_{t-s}^T
// Chunked CL=8 (NCH=1024 chunks):
//   pass1: E1_c = U_c @ Kbig          (Kbig block i = A^{7-i}B)        GEMM M=16384 K=1024 N=128
//   passE: Xent_c = sum_{j=1..16} E1_{c-j} (A^{8(j-1)})^T  (window-16) GEMM M=16384 K=2048 N=128
//   pass2: Y_c = [U_c | Xent_c] @ Wext (block-triangular + Q=CA^{t+1}) GEMM M=16384 K<=1152 N=1024
// No serial scan anywhere. Prep: k_squares (A^2..A^64 in-LDS chain) + k_mats
// (40 parallel blocks, each <=4 chained in-block 128^3 matmuls; R7: B-operand
// staged TRANSPOSED into LDS per chain step — R6's per-lane scalar global
// gather was 177 us / MfmaUtil 0.06%).
// All B-matrices stored "transposed" (row n, col k) for row-contiguous staging.
// LDS tiles XOR-swizzled (granule 8 bf16) to kill ds_read_b128 bank conflicts.

#define SEQ 8192
#define DD  128
#define NCH 1024
#define WIN 16

typedef __bf16 bf16t;
typedef __bf16 bf16x8 __attribute__((ext_vector_type(8)));
typedef float  f32x4  __attribute__((ext_vector_type(4)));

#define MFMA(a,b,c) __builtin_amdgcn_mfma_f32_16x16x32_bf16(a,b,c,0,0,0)

// swizzled column index within a row; granule = 8 bf16 = 16B
__device__ __forceinline__ int swc(int r, int c) {
    int g = c >> 3;
    g = (g & ~7) | ((g ^ r) & 7);
    return (g << 3) | (c & 7);
}
__device__ __forceinline__ bf16x8 ldf64(const bf16t* T, int row, int q, int lane) {
    int c = q * 32 + ((lane >> 4) << 3);
    return *(const bf16x8*)(T + row * 64 + swc(row, c));
}
__device__ __forceinline__ bf16x8 ldf128(const bf16t* T, int row, int q, int lane) {
    int c = q * 32 + ((lane >> 4) << 3);
    return *(const bf16x8*)(T + row * 128 + swc(row, c));
}
__device__ __forceinline__ bf16x8 cvt8(float4 a, float4 b) {
    bf16x8 r;
    r[0]=(bf16t)a.x; r[1]=(bf16t)a.y; r[2]=(bf16t)a.z; r[3]=(bf16t)a.w;
    r[4]=(bf16t)b.x; r[5]=(bf16t)b.y; r[6]=(bf16t)b.z; r[7]=(bf16t)b.w;
    return r;
}
__device__ __forceinline__ bf16x8 bzero8() {
    bf16x8 z;
#pragma unroll
    for (int e = 0; e < 8; e++) z[e] = (bf16t)0.f;
    return z;
}
__device__ __forceinline__ f32x4 fzero4() { f32x4 z = {0.f, 0.f, 0.f, 0.f}; return z; }

// ---------------- k_squares: block 0: A^2,A^4,A^8,A^16,A^32,A^64 (in-LDS chain);
// blocks >0: zero Wext; block 1 also writes identity ----------------
__global__ __launch_bounds__(512, 2) void k_squares(const float* __restrict__ A,
                                                    float* __restrict__ Sq,
                                                    float* __restrict__ Iden,
                                                    bf16t* __restrict__ Wext) {
    if (blockIdx.x > 0) {
        bf16x8 z = bzero8();
        long t0 = (long)(blockIdx.x - 1) * 512 + threadIdx.x;
        const long tot = 1024L * 1152 / 8;
        for (long i = t0; i < tot; i += (long)(gridDim.x - 1) * 512)
            *(bf16x8*)(Wext + i * 8) = z;
        if (blockIdx.x == 1)
            for (int i = threadIdx.x; i < 16384; i += 512)
                Iden[i] = ((i >> 7) == (i & 127)) ? 1.f : 0.f;
        return;
    }
    __shared__ bf16t H0[128*128], T0[128*128], H1[128*128], T1[128*128];  // 128 KB
    int tid = threadIdx.x, lane = tid & 63, wid = tid >> 6;
    {   // load A -> H0 (row-major swz) and T0 (transposed swz)
        int r = tid >> 2, c0 = (tid & 3) * 32;
#pragma unroll
        for (int e = 0; e < 4; e++) {
            float4 va = *(const float4*)(A + r*128 + c0 + e*8);
            float4 vb = *(const float4*)(A + r*128 + c0 + e*8 + 4);
            bf16x8 h = cvt8(va, vb);
            *(bf16x8*)(H0 + r*128 + swc(r, c0 + e*8)) = h;
#pragma unroll
            for (int x = 0; x < 8; x++) {
                int cc = c0 + e*8 + x;
                T0[cc*128 + swc(cc, r)] = h[x];
            }
        }
    }
    __syncthreads();
    bf16t *cH = H0, *cT = T0, *nH = H1, *nT = T1;
    for (int lvl = 0; lvl < 6; lvl++) {
        f32x4 acc[8];
#pragma unroll
        for (int nf = 0; nf < 8; nf++) acc[nf] = fzero4();
        int m = 16*wid + (lane & 15);
#pragma unroll
        for (int q = 0; q < 4; q++) {
            bf16x8 af = ldf128(cH, m, q, lane);
#pragma unroll
            for (int nf = 0; nf < 8; nf++) {
                bf16x8 bv = ldf128(cT, nf*16 + (lane & 15), q, lane);
                acc[nf] = MFMA(af, bv, acc[nf]);
            }
        }
#pragma unroll
        for (int nf = 0; nf < 8; nf++)
#pragma unroll
            for (int rr = 0; rr < 4; rr++) {
                int row = 16*wid + ((lane >> 4) << 2) + rr;
                int col = nf*16 + (lane & 15);
                float v = acc[nf][rr];
                bf16t hv = (bf16t)v;
                nH[row*128 + swc(row, col)] = hv;
                nT[col*128 + swc(col, row)] = hv;
                Sq[lvl*16384 + row*128 + col] = v;
            }
        __syncthreads();
        bf16t* t;
        t = cH; cH = nH; nH = t;
        t = cT; cT = nT; nT = t;
    }
}

// ---------------- k_mats: 40 blocks, each a chain product, packed bf16 ----------------
// globals: 0=A 1=B 2=C 3=A2 4=A4 5=A8 6=A16 7=A32 8=A64 9=I
// R7: chain-step B-operand staged transposed into LDS (coalesced global reads),
// MFMA feeds from LDS — no per-lane scalar global gathers.
__global__ __launch_bounds__(512) void k_mats(const float* __restrict__ A,
                                              const float* __restrict__ B,
                                              const float* __restrict__ C,
                                              const float* __restrict__ Dm,
                                              const float* __restrict__ Sq,
                                              const float* __restrict__ Iden,
                                              bf16t* __restrict__ Kbig,
                                              bf16t* __restrict__ Dist,
                                              bf16t* __restrict__ Wext) {
    __shared__ bf16t Hc[128*128], Hn[128*128], Tg[128*128];   // 96 KB
    int tid = threadIdx.x, lane = tid & 63, wid = tid >> 6;
    int bid = blockIdx.x;
    const float* G[10] = {A, B, C, Sq, Sq + 16384, Sq + 2*16384,
                          Sq + 3*16384, Sq + 4*16384, Sq + 5*16384, Iden};
    int ch[6]; int nc = 0;
    bf16t* dst0 = nullptr; long dstride = 0;
    bool plusD = false, isW = false; int wd = 0;
    if (bid < 14) {                       // P^j = A^(8j) -> Dist col-block 15-j
        int j = bid + 2;
        if (j & 8) ch[nc++] = 8;
        if (j & 4) ch[nc++] = 7;
        if (j & 2) ch[nc++] = 6;
        if (j & 1) ch[nc++] = 5;
        if (nc == 1) ch[nc++] = 9;
        dst0 = Dist + (15 - j) * 128; dstride = 2048;
    } else if (bid == 14) { ch[nc++] = 9; ch[nc++] = 9; dst0 = Dist + 15*128; dstride = 2048; }
    else if (bid == 15)   { ch[nc++] = 5; ch[nc++] = 9; dst0 = Dist + 14*128; dstride = 2048; }
    else if (bid < 24) {                  // S_d = A^d B -> Kbig col-block 7-d
        int d = bid - 16;
        if (d & 4) ch[nc++] = 4;
        if (d & 2) ch[nc++] = 3;
        if (d & 1) ch[nc++] = 0;
        ch[nc++] = 1;
        if (nc == 1) ch[nc++] = 9;
        dst0 = Kbig + (7 - d) * 128; dstride = 1024;
    } else if (bid < 32) {                // Q_k = C A^k -> Wext rows (k-1)*128, col 1024
        int k = bid - 23;
        ch[nc++] = 2;
        if (k & 8) ch[nc++] = 5;
        if (k & 4) ch[nc++] = 4;
        if (k & 2) ch[nc++] = 3;
        if (k & 1) ch[nc++] = 0;
        dst0 = Wext + (long)(k - 1) * 128 * 1152 + 1024; dstride = 1152;
    } else {                              // W_d = C A^d B (+D if d=0) -> slots (t, t-d)
        wd = bid - 32; isW = true;
        ch[nc++] = 2;
        if (wd & 4) ch[nc++] = 4;
        if (wd & 2) ch[nc++] = 3;
        if (wd & 1) ch[nc++] = 0;
        ch[nc++] = 1;
        plusD = (wd == 0);
    }
    {   // stage G[ch[0]] into Hc (row-major swz)
        const float* g0 = G[ch[0]];
        int r = tid >> 2, c0 = (tid & 3) * 32;
#pragma unroll
        for (int e = 0; e < 4; e++) {
            float4 va = *(const float4*)(g0 + r*128 + c0 + e*8);
            float4 vb = *(const float4*)(g0 + r*128 + c0 + e*8 + 4);
            *(bf16x8*)(Hc + r*128 + swc(r, c0 + e*8)) = cvt8(va, vb);
        }
    }
    f32x4 acc[8];
    bf16t* cur = Hc; bf16t* nxt = Hn;
    for (int i = 1; i < nc; i++) {
        const float* g = G[ch[i]];
        __syncthreads();                  // prior Tg reads + cur/nxt writes done
        {   // stage g transposed into Tg (coalesced reads, swz scatter)
            int r = tid >> 2, c0 = (tid & 3) * 32;
#pragma unroll
            for (int e = 0; e < 4; e++) {
                float4 va = *(const float4*)(g + r*128 + c0 + e*8);
                float4 vb = *(const float4*)(g + r*128 + c0 + e*8 + 4);
                bf16x8 h = cvt8(va, vb);
#pragma unroll
                for (int x = 0; x < 8; x++) {
                    int cc = c0 + e*8 + x;
                    Tg[cc*128 + swc(cc, r)] = h[x];
                }
            }
        }
        __syncthreads();
#pragma unroll
        for (int nf = 0; nf < 8; nf++) acc[nf] = fzero4();
        int m = 16*wid + (lane & 15);
#pragma unroll
        for (int q = 0; q < 4; q++) {
            bf16x8 af = ldf128(cur, m, q, lane);
#pragma unroll
            for (int nf = 0; nf < 8; nf++) {
                bf16x8 bv = ldf128(Tg, nf*16 + (lane & 15), q, lane);
                acc[nf] = MFMA(af, bv, acc[nf]);
            }
        }
        if (i + 1 < nc) {
#pragma unroll
            for (int nf = 0; nf < 8; nf++)
#pragma unroll
                for (int rr = 0; rr < 4; rr++) {
                    int row = 16*wid + ((lane >> 4) << 2) + rr;
                    int col = nf*16 + (lane & 15);
                    nxt[row*128 + swc(row, col)] = (bf16t)acc[nf][rr];
                }
            bf16t* t = cur; cur = nxt; nxt = t;
        }
    }
#pragma unroll
    for (int nf = 0; nf < 8; nf++)
#pragma unroll
        for (int rr = 0; rr < 4; rr++) {
            int row = 16*wid + ((lane >> 4) << 2) + rr;
            int col = nf*16 + (lane & 15);
            float v = acc[nf][rr];
            if (plusD) v += Dm[row*128 + col];
            bf16t hv = (bf16t)v;
            if (!isW) dst0[(long)row * dstride + col] = hv;
            else
                for (int t = wd; t < 8; t++)
                    Wext[((long)t*128 + row) * 1152 + (t - wd)*128 + col] = hv;
        }
}

// ---------------- pass1: E1 = U @ Kbig ; BM=64(4 chunks) BN=128 BK=64, 4 waves ----------------
__global__ __launch_bounds__(256, 2) void k_pass1(const float* __restrict__ u,
                                                  const bf16t* __restrict__ Kbig,
                                                  bf16t* __restrict__ E1) {
    __shared__ bf16t As[2][64*64], Bs[2][128*64];    // 48 KB
    int tid = threadIdx.x, lane = tid & 63, wid = tid >> 6;
    int wm = wid >> 1, wn = wid & 1;
    int c0 = blockIdx.x * 4;
    int ar = tid >> 2, akq = (tid & 3) << 4;
    int br = tid >> 1, bkh = (tid & 1) << 5;
    const float* ua = u + (long)(ar & 15) * SEQ * DD + (long)(c0 + (ar >> 4)) * (8 * DD) + akq;
    const bf16t* bb = Kbig + br * 1024 + bkh;
    f32x4 acc[2][4];
#pragma unroll
    for (int a = 0; a < 2; a++)
#pragma unroll
        for (int nf = 0; nf < 4; nf++) acc[a][nf] = fzero4();
    {   // stage ss=0
        float4 v0 = *(const float4*)(ua);
        float4 v1 = *(const float4*)(ua + 4);
        float4 v2 = *(const float4*)(ua + 8);
        float4 v3 = *(const float4*)(ua + 12);
        *(bf16x8*)(As[0] + ar*64 + swc(ar, akq))     = cvt8(v0, v1);
        *(bf16x8*)(As[0] + ar*64 + swc(ar, akq + 8)) = cvt8(v2, v3);
#pragma unroll
        for (int e = 0; e < 4; e++)
            *(bf16x8*)(Bs[0] + br*64 + swc(br, bkh + e*8)) = *(const bf16x8*)(bb + e*8);
    }
    __syncthreads();
    for (int ss = 0; ss < 16; ss++) {
        int p = ss & 1;
        float4 v0, v1, v2, v3; bf16x8 bv[4];
        if (ss + 1 < 16) {
            const float* pa = ua + (ss + 1) * 64;
            v0 = *(const float4*)(pa);     v1 = *(const float4*)(pa + 4);
            v2 = *(const float4*)(pa + 8); v3 = *(const float4*)(pa + 12);
#pragma unroll
            for (int e = 0; e < 4; e++) bv[e] = *(const bf16x8*)(bb + (ss + 1)*64 + e*8);
        }
#pragma unroll
        for (int q = 0; q < 2; q++) {
            bf16x8 af[2];
#pragma unroll
            for (int a = 0; a < 2; a++) af[a] = ldf64(As[p], wm*32 + a*16 + (lane & 15), q, lane);
#pragma unroll
            for (int nf = 0; nf < 4; nf++) {
                bf16x8 bfv = ldf64(Bs[p], wn*64 + nf*16 + (lane & 15), q, lane);
#pragma unroll
                for (int a = 0; a < 2; a++) acc[a][nf] = MFMA(af[a], bfv, acc[a][nf]);
            }
        }
        if (ss + 1 < 16) {
            *(bf16x8*)(As[p^1] + ar*64 + swc(ar, akq))     = cvt8(v0, v1);
            *(bf16x8*)(As[p^1] + ar*64 + swc(ar, akq + 8)) = cvt8(v2, v3);
#pragma unroll
            for (int e = 0; e < 4; e++)
                *(bf16x8*)(Bs[p^1] + br*64 + swc(br, bkh + e*8)) = bv[e];
        }
        __syncthreads();
    }
#pragma unroll
    for (int a = 0; a < 2; a++) {
        int chunk = c0 + wm*2 + a;
#pragma unroll
        for (int nf = 0; nf < 4; nf++)
#pragma unroll
            for (int rr = 0; rr < 4; rr++) {
                int b = ((lane >> 4) << 2) + rr;
                int n = wn*64 + nf*16 + (lane & 15);
                E1[((long)chunk*16 + b)*128 + n] = (bf16t)acc[a][nf][rr];
            }
    }
}

// ---------------- passE: Xent = window-16 of E1 @ Dist ----------------
__global__ __launch_bounds__(256, 2) void k_passE(const bf16t* __restrict__ E1,
                                                  const bf16t* __restrict__ Dist,
                                                  bf16t* __restrict__ Xent) {
    __shared__ bf16t As[2][64*64], Bs[2][128*64];
    int tid = threadIdx.x, lane = tid & 63, wid = tid >> 6;
    int wm = wid >> 1, wn = wid & 1;
    int c0 = blockIdx.x * 4;
    int ar = tid >> 2, akq = (tid & 3) << 4;
    int arc = ar >> 4, arb = ar & 15;
    int br = tid >> 1, bkh = (tid & 1) << 5;
    const bf16t* bb = Dist + br * 2048 + bkh;
    f32x4 acc[2][4];
#pragma unroll
    for (int a = 0; a < 2; a++)
#pragma unroll
        for (int nf = 0; nf < 4; nf++) acc[a][nf] = fzero4();
    {   // stage ss=0 (window w=0, half 0)
        int sc = c0 + arc - WIN;
        bf16x8 h0 = bzero8(), h1 = bzero8();
        if (sc >= 0) {
            const bf16t* src = E1 + ((long)sc*16 + arb)*128 + akq;
            h0 = *(const bf16x8*)(src); h1 = *(const bf16x8*)(src + 8);
        }
        *(bf16x8*)(As[0] + ar*64 + swc(ar, akq))     = h0;
        *(bf16x8*)(As[0] + ar*64 + swc(ar, akq + 8)) = h1;
#pragma unroll
        for (int e = 0; e < 4; e++)
            *(bf16x8*)(Bs[0] + br*64 + swc(br, bkh + e*8)) = *(const bf16x8*)(bb + e*8);
    }
    __syncthreads();
    for (int ss = 0; ss < 32; ss++) {
        int p = ss & 1;
        bf16x8 h0, h1, bv[4];
        if (ss + 1 < 32) {
            int s1 = ss + 1;
            int sc = c0 + arc - WIN + (s1 >> 1);
            h0 = bzero8(); h1 = bzero8();
            if (sc >= 0) {
                const bf16t* src = E1 + ((long)sc*16 + arb)*128 + (s1 & 1)*64 + akq;
                h0 = *(const bf16x8*)(src); h1 = *(const bf16x8*)(src + 8);
            }
#pragma unroll
            for (int e = 0; e < 4; e++) bv[e] = *(const bf16x8*)(bb + s1*64 + e*8);
        }
#pragma unroll
        for (int q = 0; q < 2; q++) {
            bf16x8 af[2];
#pragma unroll
            for (int a = 0; a < 2; a++) af[a] = ldf64(As[p], wm*32 + a*16 + (lane & 15), q, lane);
#pragma unroll
            for (int nf = 0; nf < 4; nf++) {
                bf16x8 bfv = ldf64(Bs[p], wn*64 + nf*16 + (lane & 15), q, lane);
#pragma unroll
                for (int a = 0; a < 2; a++) acc[a][nf] = MFMA(af[a], bfv, acc[a][nf]);
            }
        }
        if (ss + 1 < 32) {
            *(bf16x8*)(As[p^1] + ar*64 + swc(ar, akq))     = h0;
            *(bf16x8*)(As[p^1] + ar*64 + swc(ar, akq + 8)) = h1;
#pragma unroll
            for (int e = 0; e < 4; e++)
                *(bf16x8*)(Bs[p^1] + br*64 + swc(br, bkh + e*8)) = bv[e];
        }
        __syncthreads();
    }
#pragma unroll
    for (int a = 0; a < 2; a++) {
        int chunk = c0 + wm*2 + a;
#pragma unroll
        for (int nf = 0; nf < 4; nf++)
#pragma unroll
            for (int rr = 0; rr < 4; rr++) {
                int b = ((lane >> 4) << 2) + rr;
                int n = wn*64 + nf*16 + (lane & 15);
                Xent[((long)chunk*16 + b)*128 + n] = (bf16t)acc[a][nf][rr];
            }
    }
}

// ---------------- pass2: Y = [U|Xent] @ Wext ; BM=256(16 chunks) BN=128(one t) ----------------
// 8 waves (4 wm x 2 wn); paired t-jobs {p, 7-p} => uniform 22 substeps/block.
// XCD-swizzle: the 4 p-blocks of one gm land on the same XCD for u L2-reuse.
__global__ __launch_bounds__(512, 2) void k_pass2(const float* __restrict__ u,
                                                  const bf16t* __restrict__ Xent,
                                                  const bf16t* __restrict__ Wext,
                                                  float* __restrict__ out) {
    __shared__ bf16t As[2][256*64], Bs[2][128*64];   // 96 KB
    int tid = threadIdx.x, lane = tid & 63, wid = tid >> 6;
    int wm = wid >> 1, wn = wid & 1;
    int i = blockIdx.x;
    int gm = (i & 7) * 8 + ((i >> 3) >> 2);
    int pp = (i >> 3) & 3;
    int c0 = gm * 16;
    int ar = tid >> 1, akh = (tid & 1) << 5;
    int arc = ar >> 4, arb = ar & 15;
    int br = tid >> 2, bkq = (tid & 3) << 4;
    const float* ua = u + (long)arb * SEQ * DD + (long)(c0 + arc) * (8 * DD) + akh;
    const bf16t* xa = Xent + ((long)(c0 + arc) * 16 + arb) * 128 + akh;

    for (int job = 0; job < 2; job++) {
        int t = job ? (7 - pp) : pp;
        const bf16t* bb = Wext + (long)(t * 128 + br) * 1152 + bkq;
        int NS = 2*t + 4;
        int nu = 2*t + 2;                 // u-substeps; then 2 xent substeps
        f32x4 acc[4][4];
#pragma unroll
        for (int a = 0; a < 4; a++)
#pragma unroll
            for (int nf = 0; nf < 4; nf++) acc[a][nf] = fzero4();
        {   // stage ss=0 (always a u-substep)
            float4 v[8];
#pragma unroll
            for (int e = 0; e < 8; e++) v[e] = *(const float4*)(ua + e*4);
#pragma unroll
            for (int e = 0; e < 4; e++)
                *(bf16x8*)(As[0] + ar*64 + swc(ar, akh + e*8)) = cvt8(v[2*e], v[2*e+1]);
            *(bf16x8*)(Bs[0] + br*64 + swc(br, bkq))     = *(const bf16x8*)(bb);
            *(bf16x8*)(Bs[0] + br*64 + swc(br, bkq + 8)) = *(const bf16x8*)(bb + 8);
        }
        __syncthreads();
        for (int ss = 0; ss < NS; ss++) {
            int p = ss & 1;
            float4 v[8]; bf16x8 xv[4], bv0, bv1;
            bool nxU = true;
            if (ss + 1 < NS) {
                int s1 = ss + 1;
                nxU = s1 < nu;
                if (nxU) {
                    const float* pa = ua + s1 * 64;
#pragma unroll
                    for (int e = 0; e < 8; e++) v[e] = *(const float4*)(pa + e*4);
                } else {
                    const bf16t* px = xa + (s1 - nu) * 64;
#pragma unroll
                    for (int e = 0; e < 4; e++) xv[e] = *(const bf16x8*)(px + e*8);
                }
                long kB = nxU ? (long)s1 * 64 : 1024 + (long)(s1 - nu) * 64;
                bv0 = *(const bf16x8*)(bb + kB);
                bv1 = *(const bf16x8*)(bb + kB + 8);
            }
#pragma unroll
            for (int q = 0; q < 2; q++) {
                bf16x8 af[4];
#pragma unroll
                for (int a = 0; a < 4; a++)
                    af[a] = ldf64(As[p], wm*64 + a*16 + (lane & 15), q, lane);
#pragma unroll
                for (int nf = 0; nf < 4; nf++) {
                    bf16x8 bfv = ldf64(Bs[p], wn*64 + nf*16 + (lane & 15), q, lane);
#pragma unroll
                    for (int a = 0; a < 4; a++) acc[a][nf] = MFMA(af[a], bfv, acc[a][nf]);
                }
            }
            if (ss + 1 < NS) {
                if (nxU) {
#pragma unroll
                    for (int e = 0; e < 4; e++)
                        *(bf16x8*)(As[p^1] + ar*64 + swc(ar, akh + e*8)) = cvt8(v[2*e], v[2*e+1]);
                } else {
#pragma unroll
                    for (int e = 0; e < 4; e++)
                        *(bf16x8*)(As[p^1] + ar*64 + swc(ar, akh + e*8)) = xv[e];
                }
                *(bf16x8*)(Bs[p^1] + br*64 + swc(br, bkq))     = bv0;
                *(bf16x8*)(Bs[p^1] + br*64 + swc(br, bkq + 8)) = bv1;
            }
            __syncthreads();
        }
#pragma unroll
        for (int a = 0; a < 4; a++) {
            int cl = wm*4 + a;
#pragma unroll
            for (int nf = 0; nf < 4; nf++)
#pragma unroll
                for (int rr = 0; rr < 4; rr++) {
                    int b = ((lane >> 4) << 2) + rr;
                    int dout = wn*64 + nf*16 + (lane & 15);
                    out[((long)b*SEQ + (long)(c0 + cl)*8 + t)*128 + dout] = acc[a][nf][rr];
                }
        }
        __syncthreads();
    }
}

extern "C" void kernel_launch(void* const* d_in, const int* in_sizes, int n_in,
                              void* d_out, int out_size, void* d_ws, size_t ws_size,
                              hipStream_t stream) {
    (void)in_sizes; (void)n_in; (void)out_size; (void)ws_size;
    const float* u = (const float*)d_in[0];
    const float* A = (const float*)d_in[1];
    const float* B = (const float*)d_in[2];
    const float* C = (const float*)d_in[3];
    const float* D = (const float*)d_in[4];
    float* out = (float*)d_out;
    // ws: Sq 6x16K f32 | Iden 16K f32 | Kbig 128x1024 bf16 | Dist 128x2048 bf16
    //   | Wext 1024x1152 bf16 | Xent 1024x16x128 bf16   (~7.44 MB)
    float* Sq   = (float*)d_ws;
    float* Iden = Sq + 6 * 16384;
    bf16t* Kbig = (bf16t*)(Iden + 16384);
    bf16t* Dist = Kbig + 128 * 1024;
    bf16t* Wext = Dist + 128 * 2048;
    bf16t* Xent = Wext + (long)1024 * 1152;
    bf16t* E1   = (bf16t*)d_out;   // borrowed: dead before pass2 overwrites out

    k_squares<<<65, 512, 0, stream>>>(A, Sq, Iden, Wext);
    k_mats  <<<40, 512, 0, stream>>>(A, B, C, D, Sq, Iden, Kbig, Dist, Wext);
    k_pass1 <<<256, 256, 0, stream>>>(u, Kbig, E1);
    k_passE <<<256, 256, 0, stream>>>(E1, Dist, Xent);
    k_pass2 <<<256, 512, 0, stream>>>(u, Xent, Wext, out);
}

// Round 8
// 124.455 us; speedup vs baseline: 2.2310x; 1.2573x over previous
//
#include <hip/hip_runtime.h>

// LSSM via truncated causal convolution (rho(A)=0.9 => A^96 ~ 4e-5, negligible).
//   W_0 = CB + D, W_d = C A^d B;  y_t = sum_{s<=t} u_s W_{t-s}^T
// Chunked CL=8 (1024 chunks), WIN=12 chunks of history (96 steps):
//   pass1: E1_c   = U_c @ KbigT              (chunk-local end states)
//   passE: Xent_c = sum_{j=1..12} E1_{c-j} (A^{8(j-1)})^T   (entry states)
//   pass2: Y_c[t] = sum_{p<=t} U_c[p] W_{t-p}^T + Xent_c (C A^{t+1})^T
// R8 structure: every pass block stages its whole A-tile to LDS ONCE
// (single barrier), then computes barrier-free; B-operands are reg-cached
// or read from L2 (all B matrices <= 400 KB). pass2 does ALL 8 t's per
// block using the 8 distinct W_d -> u is read exactly once.

#define SEQ 8192
#define DD  128
#define WIN 12

typedef __bf16 bf16t;
typedef __bf16 bf16x8 __attribute__((ext_vector_type(8)));
typedef float  f32x4  __attribute__((ext_vector_type(4)));

#define MFMA(a,b,c) __builtin_amdgcn_mfma_f32_16x16x32_bf16(a,b,c,0,0,0)

// swizzled column index within a row; granule = 8 bf16 = 16B
__device__ __forceinline__ int swc(int r, int c) {
    int g = c >> 3;
    g = (g & ~7) | ((g ^ r) & 7);
    return (g << 3) | (c & 7);
}
__device__ __forceinline__ bf16x8 lds_frag(const bf16t* T, int stride, int row, int col) {
    return *(const bf16x8*)(T + row * stride + swc(row, col));
}
__device__ __forceinline__ bf16x8 cvt8(float4 a, float4 b) {
    bf16x8 r;
    r[0]=(bf16t)a.x; r[1]=(bf16t)a.y; r[2]=(bf16t)a.z; r[3]=(bf16t)a.w;
    r[4]=(bf16t)b.x; r[5]=(bf16t)b.y; r[6]=(bf16t)b.z; r[7]=(bf16t)b.w;
    return r;
}
__device__ __forceinline__ bf16x8 bzero8() {
    bf16x8 z;
#pragma unroll
    for (int e = 0; e < 8; e++) z[e] = (bf16t)0.f;
    return z;
}
__device__ __forceinline__ f32x4 fzero4() { f32x4 z = {0.f, 0.f, 0.f, 0.f}; return z; }

// ---------------- k_squares: block 0: A^2..A^64 in-LDS chain -> Sq (fp32);
// block 1: identity matrix + zero E1pad head ----------------
__global__ __launch_bounds__(512, 2) void k_squares(const float* __restrict__ A,
                                                    float* __restrict__ Sq,
                                                    float* __restrict__ Iden,
                                                    bf16t* __restrict__ E1pad) {
    int tid = threadIdx.x, lane = tid & 63, wid = tid >> 6;
    if (blockIdx.x == 1) {
        for (int i = tid; i < 16384; i += 512)
            Iden[i] = ((i >> 7) == (i & 127)) ? 1.f : 0.f;
        bf16x8 z = bzero8();
        for (int i = tid; i < WIN * 16 * 128 / 8; i += 512)
            *(bf16x8*)(E1pad + i * 8) = z;
        return;
    }
    __shared__ bf16t H0[128*128], T0[128*128], H1[128*128], T1[128*128];  // 128 KB
    {   // load A -> H0 (row-major swz) and T0 (transposed swz)
        int r = tid >> 2, c0 = (tid & 3) * 32;
#pragma unroll
        for (int e = 0; e < 4; e++) {
            float4 va = *(const float4*)(A + r*128 + c0 + e*8);
            float4 vb = *(const float4*)(A + r*128 + c0 + e*8 + 4);
            bf16x8 h = cvt8(va, vb);
            *(bf16x8*)(H0 + r*128 + swc(r, c0 + e*8)) = h;
#pragma unroll
            for (int x = 0; x < 8; x++) {
                int cc = c0 + e*8 + x;
                T0[cc*128 + swc(cc, r)] = h[x];
            }
        }
    }
    __syncthreads();
    bf16t *cH = H0, *cT = T0, *nH = H1, *nT = T1;
    for (int lvl = 0; lvl < 6; lvl++) {
        f32x4 acc[8];
#pragma unroll
        for (int nf = 0; nf < 8; nf++) acc[nf] = fzero4();
        int m = 16*wid + (lane & 15);
#pragma unroll
        for (int q = 0; q < 4; q++) {
            bf16x8 af = lds_frag(cH, 128, m, q*32 + ((lane >> 4) << 3));
#pragma unroll
            for (int nf = 0; nf < 8; nf++) {
                bf16x8 bv = lds_frag(cT, 128, nf*16 + (lane & 15), q*32 + ((lane >> 4) << 3));
                acc[nf] = MFMA(af, bv, acc[nf]);
            }
        }
#pragma unroll
        for (int nf = 0; nf < 8; nf++)
#pragma unroll
            for (int rr = 0; rr < 4; rr++) {
                int row = 16*wid + ((lane >> 4) << 2) + rr;
                int col = nf*16 + (lane & 15);
                float v = acc[nf][rr];
                bf16t hv = (bf16t)v;
                nH[row*128 + swc(row, col)] = hv;
                nT[col*128 + swc(col, row)] = hv;
                Sq[lvl*16384 + row*128 + col] = v;
            }
        __syncthreads();
        bf16t* t;
        t = cH; cH = nH; nH = t;
        t = cT; cT = nT; nT = t;
    }
}

// ---------------- k_mats: 36 blocks, each a chain product, row-major bf16 out --------
// globals: 0=A 1=B 2=C 3=A2 4=A4 5=A8 6=A16 7=A32 8=A64 9=I
// bid 0..7:  KbigT block: A^d B  -> KbigT cols (7-d)*128, stride 1024
// bid 8..19: DistT j-1=e:  A^{8e} -> DistT + e*16384
// bid 20..27: WdT d: C A^d B (+D if d=0) -> WdT + d*16384
// bid 28..35: QT t: C A^{t+1} -> QT + t*16384
__global__ __launch_bounds__(512) void k_mats(const float* __restrict__ A,
                                              const float* __restrict__ B,
                                              const float* __restrict__ C,
                                              const float* __restrict__ Dm,
                                              const float* __restrict__ Sq,
                                              const float* __restrict__ Iden,
                                              bf16t* __restrict__ KbigT,
                                              bf16t* __restrict__ DistT,
                                              bf16t* __restrict__ WdT,
                                              bf16t* __restrict__ QT) {
    __shared__ bf16t Hc[128*128], Hn[128*128], Tg[128*128];   // 96 KB
    int tid = threadIdx.x, lane = tid & 63, wid = tid >> 6;
    int bid = blockIdx.x;
    const float* G[10] = {A, B, C, Sq, Sq + 16384, Sq + 2*16384,
                          Sq + 3*16384, Sq + 4*16384, Sq + 5*16384, Iden};
    int ch[6]; int nc = 0;
    bf16t* dst = nullptr; long dstride = 128;
    bool plusD = false;
    if (bid < 8) {                        // A^d B
        int d = bid;
        if (d & 4) ch[nc++] = 4;
        if (d & 2) ch[nc++] = 3;
        if (d & 1) ch[nc++] = 0;
        ch[nc++] = 1;
        if (nc == 1) ch[nc++] = 9;
        dst = KbigT + (7 - d) * 128; dstride = 1024;
    } else if (bid < 20) {                // A^{8e}, e = 0..11
        int e = bid - 8;
        if (e & 8) ch[nc++] = 8;
        if (e & 4) ch[nc++] = 7;
        if (e & 2) ch[nc++] = 6;
        if (e & 1) ch[nc++] = 5;
        if (nc == 0) ch[nc++] = 9;
        if (nc == 1) ch[nc++] = 9;
        dst = DistT + e * 16384;
    } else if (bid < 28) {                // C A^d B (+D)
        int d = bid - 20;
        ch[nc++] = 2;
        if (d & 4) ch[nc++] = 4;
        if (d & 2) ch[nc++] = 3;
        if (d & 1) ch[nc++] = 0;
        ch[nc++] = 1;
        plusD = (d == 0);
        dst = WdT + d * 16384;
    } else {                              // C A^{t+1}
        int k = bid - 28 + 1;
        ch[nc++] = 2;
        if (k & 8) ch[nc++] = 5;
        if (k & 4) ch[nc++] = 4;
        if (k & 2) ch[nc++] = 3;
        if (k & 1) ch[nc++] = 0;
        dst = QT + (k - 1) * 16384;
    }
    {   // stage G[ch[0]] into Hc (row-major swz)
        const float* g0 = G[ch[0]];
        int r = tid >> 2, c0 = (tid & 3) * 32;
#pragma unroll
        for (int e = 0; e < 4; e++) {
            float4 va = *(const float4*)(g0 + r*128 + c0 + e*8);
            float4 vb = *(const float4*)(g0 + r*128 + c0 + e*8 + 4);
            *(bf16x8*)(Hc + r*128 + swc(r, c0 + e*8)) = cvt8(va, vb);
        }
    }
    f32x4 acc[8];
    bf16t* cur = Hc; bf16t* nxt = Hn;
    for (int i = 1; i < nc; i++) {
        const float* g = G[ch[i]];
        __syncthreads();
        {   // stage g transposed into Tg
            int r = tid >> 2, c0 = (tid & 3) * 32;
#pragma unroll
            for (int e = 0; e < 4; e++) {
                float4 va = *(const float4*)(g + r*128 + c0 + e*8);
                float4 vb = *(const float4*)(g + r*128 + c0 + e*8 + 4);
                bf16x8 h = cvt8(va, vb);
#pragma unroll
                for (int x = 0; x < 8; x++) {
                    int cc = c0 + e*8 + x;
                    Tg[cc*128 + swc(cc, r)] = h[x];
                }
            }
        }
        __syncthreads();
#pragma unroll
        for (int nf = 0; nf < 8; nf++) acc[nf] = fzero4();
        int m = 16*wid + (lane & 15);
#pragma unroll
        for (int q = 0; q < 4; q++) {
            bf16x8 af = lds_frag(cur, 128, m, q*32 + ((lane >> 4) << 3));
#pragma unroll
            for (int nf = 0; nf < 8; nf++) {
                bf16x8 bv = lds_frag(Tg, 128, nf*16 + (lane & 15), q*32 + ((lane >> 4) << 3));
                acc[nf] = MFMA(af, bv, acc[nf]);
            }
        }
        if (i + 1 < nc) {
#pragma unroll
            for (int nf = 0; nf < 8; nf++)
#pragma unroll
                for (int rr = 0; rr < 4; rr++) {
                    int row = 16*wid + ((lane >> 4) << 2) + rr;
                    int col = nf*16 + (lane & 15);
                    nxt[row*128 + swc(row, col)] = (bf16t)acc[nf][rr];
                }
            bf16t* t = cur; cur = nxt; nxt = t;
        }
    }
#pragma unroll
    for (int nf = 0; nf < 8; nf++)
#pragma unroll
        for (int rr = 0; rr < 4; rr++) {
            int row = 16*wid + ((lane >> 4) << 2) + rr;
            int col = nf*16 + (lane & 15);
            float v = acc[nf][rr];
            if (plusD) v += Dm[row*128 + col];
            dst[(long)row * dstride + col] = (bf16t)v;
        }
}

// ---------------- pass1: E1_c = U_c @ KbigT  (stage-once, barrier-free) ----------------
__global__ __launch_bounds__(512, 2) void k_pass1(const float* __restrict__ u,
                                                  const bf16t* __restrict__ KbigT,
                                                  bf16t* __restrict__ E1pad) {
    __shared__ bf16t U[64*1024];   // 128 KB
    int tid = threadIdx.x, lane = tid & 63, w = tid >> 6;
    int c0 = blockIdx.x * 4;
    int n = (w << 4) + (lane & 15), kg = lane >> 4;
    // reg-cache all 32 B-frags
    bf16x8 bc[32];
#pragma unroll
    for (int s = 0; s < 32; s++)
        bc[s] = *(const bf16x8*)(KbigT + n*1024 + s*32 + kg*8);
    // stage U-tile: row = cl*16+b, 1024 cols (chunk-contiguous in u)
    {
        int row = tid >> 3, cl = row >> 4, b = row & 15, cb = (tid & 7) * 128;
        const float* up = u + (long)b*SEQ*DD + (long)(c0 + cl)*1024 + cb;
#pragma unroll
        for (int e = 0; e < 16; e++) {
            float4 v0 = *(const float4*)(up + e*8);
            float4 v1 = *(const float4*)(up + e*8 + 4);
            *(bf16x8*)(U + row*1024 + swc(row, cb + e*8)) = cvt8(v0, v1);
        }
    }
    __syncthreads();
    f32x4 acc[4][2];
#pragma unroll
    for (int m = 0; m < 4; m++) { acc[m][0] = fzero4(); acc[m][1] = fzero4(); }
#pragma unroll
    for (int s = 0; s < 32; s++) {
#pragma unroll
        for (int m = 0; m < 4; m++) {
            bf16x8 af = lds_frag(U, 1024, m*16 + (lane & 15), s*32 + kg*8);
            acc[m][s & 1] = MFMA(af, bc[s], acc[m][s & 1]);
        }
    }
#pragma unroll
    for (int m = 0; m < 4; m++) {
        f32x4 a = acc[m][0] + acc[m][1];
#pragma unroll
        for (int rr = 0; rr < 4; rr++) {
            int b = (kg << 2) + rr;
            E1pad[((long)(WIN + c0 + m)*16 + b)*128 + n] = (bf16t)a[rr];
        }
    }
}

// ---------------- passE: Xent_c = window-12 E1 combine (stage-once) ----------------
__global__ __launch_bounds__(512, 2) void k_passE(const bf16t* __restrict__ E1pad,
                                                  const bf16t* __restrict__ DistT,
                                                  bf16t* __restrict__ Xent) {
    __shared__ bf16t Et[256*128];  // 64 KB: chunks c0-12 .. c0+3 (pad-resident)
    int tid = threadIdx.x, lane = tid & 63, w = tid >> 6;
    int c0 = blockIdx.x * 4;
    int n = (w << 4) + (lane & 15), kg = lane >> 4;
    {   // contiguous stage from E1pad + c0*16*128
        const bf16t* src = E1pad + (long)c0*16*128;
        int row = tid >> 1, cb = (tid & 1) * 64;
#pragma unroll
        for (int e = 0; e < 8; e++) {
            bf16x8 v = *(const bf16x8*)(src + row*128 + cb + e*8);
            *(bf16x8*)(Et + row*128 + swc(row, cb + e*8)) = v;
        }
    }
    __syncthreads();
    f32x4 acc[4][2];
#pragma unroll
    for (int m = 0; m < 4; m++) { acc[m][0] = fzero4(); acc[m][1] = fzero4(); }
#pragma unroll
    for (int j = 1; j <= WIN; j++) {
#pragma unroll
        for (int kk = 0; kk < 4; kk++) {
            bf16x8 bf = *(const bf16x8*)(DistT + (long)(j-1)*16384 + n*128 + kk*32 + kg*8);
#pragma unroll
            for (int m = 0; m < 4; m++) {
                bf16x8 af = lds_frag(Et, 128, (m + WIN - j)*16 + (lane & 15), kk*32 + kg*8);
                acc[m][j & 1] = MFMA(af, bf, acc[m][j & 1]);
            }
        }
    }
#pragma unroll
    for (int m = 0; m < 4; m++) {
        f32x4 a = acc[m][0] + acc[m][1];
#pragma unroll
        for (int rr = 0; rr < 4; rr++) {
            int b = (kg << 2) + rr;
            Xent[((long)(c0 + m)*16 + b)*128 + n] = (bf16t)a[rr];
        }
    }
}

// ---------------- pass2: Y_c[t] = conv(U_c, W) + Xent_c Q_t^T  (all 8 t per block) ----
__global__ __launch_bounds__(512, 2) void k_pass2(const float* __restrict__ u,
                                                  const bf16t* __restrict__ Xent,
                                                  const bf16t* __restrict__ WdT,
                                                  const bf16t* __restrict__ QT,
                                                  float* __restrict__ out) {
    __shared__ bf16t U[64*1024];   // 128 KB
    __shared__ bf16t X[64*128];    // 16 KB
    int tid = threadIdx.x, lane = tid & 63, w = tid >> 6;
    int c0 = blockIdx.x * 4;
    int n = (w << 4) + (lane & 15), kg = lane >> 4;
    // reg-cache W_d frags for d=0..3 (used 104/144 times)
    bf16x8 bc[4][4];
#pragma unroll
    for (int d = 0; d < 4; d++)
#pragma unroll
        for (int k4 = 0; k4 < 4; k4++)
            bc[d][k4] = *(const bf16x8*)(WdT + (long)d*16384 + n*128 + k4*32 + kg*8);
    {   // stage U-tile
        int row = tid >> 3, cl = row >> 4, b = row & 15, cb = (tid & 7) * 128;
        const float* up = u + (long)b*SEQ*DD + (long)(c0 + cl)*1024 + cb;
#pragma unroll
        for (int e = 0; e < 16; e++) {
            float4 v0 = *(const float4*)(up + e*8);
            float4 v1 = *(const float4*)(up + e*8 + 4);
            *(bf16x8*)(U + row*1024 + swc(row, cb + e*8)) = cvt8(v0, v1);
        }
    }
    {   // stage Xent tile (64 rows x 128)
        const bf16t* xs = Xent + (long)c0*16*128;
        int row = tid >> 3, cb = (tid & 7) * 16;
#pragma unroll
        for (int e = 0; e < 2; e++) {
            bf16x8 v = *(const bf16x8*)(xs + row*128 + cb + e*8);
            *(bf16x8*)(X + row*128 + swc(row, cb + e*8)) = v;
        }
    }
    __syncthreads();
    f32x4 acc[4][8];
#pragma unroll
    for (int m = 0; m < 4; m++)
#pragma unroll
        for (int t = 0; t < 8; t++) acc[m][t] = fzero4();
    // u convolution part
#pragma unroll
    for (int p = 0; p < 8; p++) {
#pragma unroll
        for (int k4 = 0; k4 < 4; k4++) {
            int s = p*4 + k4;
            bf16x8 af[4];
#pragma unroll
            for (int m = 0; m < 4; m++)
                af[m] = lds_frag(U, 1024, m*16 + (lane & 15), s*32 + kg*8);
#pragma unroll
            for (int t = p; t < 8; t++) {
                int d = t - p;
                bf16x8 bf = (d < 4) ? bc[d][k4]
                    : *(const bf16x8*)(WdT + (long)d*16384 + n*128 + k4*32 + kg*8);
#pragma unroll
                for (int m = 0; m < 4; m++) acc[m][t] = MFMA(af[m], bf, acc[m][t]);
            }
        }
    }
    // Xent @ Q_t^T part
#pragma unroll
    for (int k4 = 0; k4 < 4; k4++) {
        bf16x8 af[4];
#pragma unroll
        for (int m = 0; m < 4; m++)
            af[m] = lds_frag(X, 128, m*16 + (lane & 15), k4*32 + kg*8);
#pragma unroll
        for (int t = 0; t < 8; t++) {
            bf16x8 bf = *(const bf16x8*)(QT + (long)t*16384 + n*128 + k4*32 + kg*8);
#pragma unroll
            for (int m = 0; m < 4; m++) acc[m][t] = MFMA(af[m], bf, acc[m][t]);
        }
    }
    // epilogue: out[b][ (c0+m)*8 + t ][n]
#pragma unroll
    for (int m = 0; m < 4; m++)
#pragma unroll
        for (int t = 0; t < 8; t++)
#pragma unroll
            for (int rr = 0; rr < 4; rr++) {
                int b = (kg << 2) + rr;
                out[(long)b*SEQ*DD + ((long)(c0 + m)*8 + t)*DD + n] = acc[m][t][rr];
            }
}

extern "C" void kernel_launch(void* const* d_in, const int* in_sizes, int n_in,
                              void* d_out, int out_size, void* d_ws, size_t ws_size,
                              hipStream_t stream) {
    (void)in_sizes; (void)n_in; (void)out_size; (void)ws_size;
    const float* u = (const float*)d_in[0];
    const float* A = (const float*)d_in[1];
    const float* B = (const float*)d_in[2];
    const float* C = (const float*)d_in[3];
    const float* D = (const float*)d_in[4];
    float* out = (float*)d_out;
    // ws: Sq 6x16K f32 | Iden 16K f32 | KbigT 128x1024 | DistT 12x128^2
    //   | WdT 8x128^2 | QT 8x128^2 | E1pad (12+1024)x2048 | Xent 1024x2048  (bf16)
    // total ~10 MB
    float* Sq    = (float*)d_ws;
    float* Iden  = Sq + 6*16384;
    bf16t* KbigT = (bf16t*)(Iden + 16384);
    bf16t* DistT = KbigT + 131072;
    bf16t* WdT   = DistT + 12*16384;
    bf16t* QT    = WdT + 8*16384;
    bf16t* E1pad = QT + 8*16384;
    bf16t* Xent  = E1pad + (long)(WIN + 1024)*2048;

    k_squares<<<2,  512, 0, stream>>>(A, Sq, Iden, E1pad);
    k_mats  <<<36,  512, 0, stream>>>(A, B, C, D, Sq, Iden, KbigT, DistT, WdT, QT);
    k_pass1 <<<256, 512, 0, stream>>>(u, KbigT, E1pad);
    k_passE <<<256, 512, 0, stream>>>(E1pad, DistT, Xent);
    k_pass2 <<<256, 512, 0, stream>>>(u, Xent, WdT, QT, out);
}